// Round 3
// baseline (217.806 us; speedup 1.0000x reference)
//
#include <hip/hip_runtime.h>
#include <math.h>

#define B_ 8
#define N_ 2000
#define H_ 128
#define K_ 32
#define M_ (B_*N_)     // 16000
#define KTOT 384       // [in_agg(128) | out_agg(128) | h(128)]
#define NC 512         // cols j = d*4 + g
#define NTILES 32      // NC/16
#define NCHUNK 12      // KTOT/32

typedef __attribute__((ext_vector_type(8))) short s8_t;
typedef __attribute__((ext_vector_type(4))) float f4_t;

__device__ __forceinline__ unsigned short f2bf(float x) {
    union { float f; unsigned u; } v; v.f = x;
    unsigned r = v.u + 0x7fff + ((v.u >> 16) & 1);   // RN-even
    return (unsigned short)(r >> 16);
}
__device__ __forceinline__ float bf2f(unsigned short b) {
    union { unsigned u; float f; } v; v.u = (unsigned)b << 16; return v.f;
}
__device__ __forceinline__ float sigm_(float x) { return 1.f / (1.f + __expf(-x)); }
__device__ __forceinline__ float tanh_(float x) { return 2.f / (1.f + __expf(-2.f * x)) - 1.f; }

__device__ __forceinline__ float pickv(f4_t A, int m) {
    float ab = (m & 1) ? A.y : A.x;
    float cd = (m & 1) ? A.w : A.z;
    return (m & 2) ? cd : ab;
}
__device__ __forceinline__ float pick4(float u0, float u1, float u2, float u3, int m) {
    float ab = (m & 1) ? u1 : u0;
    float cd = (m & 1) ? u3 : u2;
    return (m & 2) ? cd : ab;
}

// split 8 fp32 -> 8 bf16 hi (16B) + 8 bf16 lo (16B), store to LDS
__device__ __forceinline__ void split_store(short* ph, short* pl, const float* f) {
    unsigned h[8], l[8];
    #pragma unroll
    for (int i = 0; i < 8; ++i) {
        unsigned short hs = f2bf(f[i]);
        h[i] = hs;
        l[i] = f2bf(f[i] - bf2f(hs));
    }
    uint4 H, L;
    H.x = h[0] | (h[1] << 16); H.y = h[2] | (h[3] << 16);
    H.z = h[4] | (h[5] << 16); H.w = h[6] | (h[7] << 16);
    L.x = l[0] | (l[1] << 16); L.y = l[2] | (l[3] << 16);
    L.z = l[4] | (l[5] << 16); L.w = l[6] | (l[7] << 16);
    *(uint4*)ph = H;
    *(uint4*)pl = L;
}

// W in per-lane MFMA B-fragment order: element (ntile, chunk, lane, e) =
// W[col = ntile*16 + (lane&15)][k = chunk*32 + (lane>>4)*8 + e], col j = d*4+g.
__global__ __launch_bounds__(512)
void prep_kernel(const float* __restrict__ w_in,
                 const float* __restrict__ w_out,
                 const float* __restrict__ u_in,
                 const float* __restrict__ u_out,
                 unsigned short* __restrict__ wp_hi,
                 unsigned short* __restrict__ wp_lo) {
    int blk = blockIdx.x;            // ntile*NCHUNK + chunk
    int ntile = blk / NCHUNK, chunk = blk % NCHUNK;
    int t = threadIdx.x;
    int lane = t >> 3, e = t & 7;
    int col = ntile * 16 + (lane & 15);
    int k = chunk * 32 + (lane >> 4) * 8 + e;
    int d = col >> 2, g = col & 3;
    float v;
    if (k < 128) {
        v = w_in[(g * 128 + k) * 128 + d];
    } else if (k < 256) {
        v = w_out[(g * 128 + (k - 128)) * 128 + d];
    } else {
        int kk = k - 256;
        v = u_in[(g * 128 + kk) * 128 + d] + u_out[(g * 128 + kk) * 128 + d];
    }
    unsigned short hs = f2bf(v);
    wp_hi[(size_t)blk * 512 + t] = hs;
    wp_lo[(size_t)blk * 512 + t] = f2bf(v - bf2f(hs));
}

// Fused layer: gather+agg (fp32) -> split-bf16 A panel in LDS -> barrier-free
// MFMA K-loop (W streamed from L2 in fragment layout) -> fused LSTM gates.
__global__ __launch_bounds__(512, 4)
void fused_layer(const float* __restrict__ h_src,
                 const int* __restrict__ in_idx,
                 const float* __restrict__ in_mask,
                 const int* __restrict__ out_idx,
                 const float* __restrict__ out_mask,
                 const unsigned short* __restrict__ wp_hi,
                 const unsigned short* __restrict__ wp_lo,
                 const float* __restrict__ bias,
                 const float* __restrict__ c_src,
                 float* __restrict__ c_dst,
                 float* __restrict__ h_dst) {
    // chunk-planed panel: [chunk][m(32)][k(32)] shorts; 24 KB per plane
    __shared__ short As_hi[NCHUNK * 32 * 32];
    __shared__ short As_lo[NCHUNK * 32 * 32];

    int tid = threadIdx.x;
    int row0 = blockIdx.x * 32;

    // ---------------- gather / aggregate phase ----------------
    {
        int r = tid >> 4;            // 0..31 row within block
        int p = tid & 15;            // dim group: dims p*8 .. p*8+7
        int d0 = p * 8;
        int row = row0 + r;
        int b = row / N_;
        const float* hb = h_src + (size_t)b * N_ * H_;
        const int*   pii = in_idx  + (size_t)row * K_;
        const float* pim = in_mask + (size_t)row * K_;
        const int*   poi = out_idx + (size_t)row * K_;
        const float* pom = out_mask + (size_t)row * K_;

        float ai[8] = {0,0,0,0,0,0,0,0};
        float ao[8] = {0,0,0,0,0,0,0,0};
        #pragma unroll 4
        for (int k = 0; k < K_; ++k) {
            int   ii = pii[k];
            float mi = pim[k];
            int   oi = poi[k];
            float mo = pom[k];
            const float* pv = hb + (size_t)ii * H_ + d0;
            const float* pw = hb + (size_t)oi * H_ + d0;
            float4 v0 = *(const float4*)pv;
            float4 v1 = *(const float4*)(pv + 4);
            float4 w0 = *(const float4*)pw;
            float4 w1 = *(const float4*)(pw + 4);
            ai[0] += mi * v0.x; ai[1] += mi * v0.y; ai[2] += mi * v0.z; ai[3] += mi * v0.w;
            ai[4] += mi * v1.x; ai[5] += mi * v1.y; ai[6] += mi * v1.z; ai[7] += mi * v1.w;
            ao[0] += mo * w0.x; ao[1] += mo * w0.y; ao[2] += mo * w0.z; ao[3] += mo * w0.w;
            ao[4] += mo * w1.x; ao[5] += mo * w1.y; ao[6] += mo * w1.z; ao[7] += mo * w1.w;
        }
        // own h row (u-term input)
        const float* ph = h_src + (size_t)row * H_ + d0;
        float4 u0 = *(const float4*)ph;
        float4 u1 = *(const float4*)(ph + 4);
        float hh[8] = {u0.x, u0.y, u0.z, u0.w, u1.x, u1.y, u1.z, u1.w};

        int ci  = p >> 2;            // chunk sub-index 0..3
        int off = (p & 3) * 8;       // short offset within 32-k chunk
        int base_in = ((ci)     * 32 + r) * 32 + off;
        int base_ou = ((4 + ci) * 32 + r) * 32 + off;
        int base_hh = ((8 + ci) * 32 + r) * 32 + off;
        split_store(&As_hi[base_in], &As_lo[base_in], ai);
        split_store(&As_hi[base_ou], &As_lo[base_ou], ao);
        split_store(&As_hi[base_hh], &As_lo[base_hh], hh);
    }
    __syncthreads();

    // ---------------- MFMA phase (no barriers) ----------------
    int lane = tid & 63;
    int w = tid >> 6;                // 0..7, wave tile = 32 rows x 64 cols
    int ml = lane & 15;
    int kg = lane >> 4;

    f4_t zero = {0.f, 0.f, 0.f, 0.f};
    f4_t acc[2][4];
    #pragma unroll
    for (int i = 0; i < 2; ++i)
        #pragma unroll
        for (int j = 0; j < 4; ++j) acc[i][j] = zero;

    int w4 = w * 4;
    #pragma unroll 2
    for (int c = 0; c < NCHUNK; ++c) {
        s8_t a_hi[2], a_lo[2];
        #pragma unroll
        for (int i = 0; i < 2; ++i) {
            int m = i * 16 + ml;
            a_hi[i] = *(const s8_t*)&As_hi[(c * 32 + m) * 32 + kg * 8];
            a_lo[i] = *(const s8_t*)&As_lo[(c * 32 + m) * 32 + kg * 8];
        }
        #pragma unroll
        for (int j = 0; j < 4; ++j) {
            size_t boff = (((size_t)(w4 + j) * NCHUNK + c) * 64 + lane) * 8;
            s8_t b_hi = *(const s8_t*)(wp_hi + boff);
            s8_t b_lo = *(const s8_t*)(wp_lo + boff);
            #pragma unroll
            for (int i = 0; i < 2; ++i) {
                acc[i][j] = __builtin_amdgcn_mfma_f32_16x16x32_bf16(a_hi[i], b_hi, acc[i][j], 0, 0, 0);
                acc[i][j] = __builtin_amdgcn_mfma_f32_16x16x32_bf16(a_hi[i], b_lo, acc[i][j], 0, 0, 0);
                acc[i][j] = __builtin_amdgcn_mfma_f32_16x16x32_bf16(a_lo[i], b_hi, acc[i][j], 0, 0, 0);
            }
        }
    }

    // ---------------- epilogue: gates + cell/h update ----------------
    // C layout: col = lane&15, row = (lane>>4)*4 + reg. Quad shares d; gate g = lane&3.
    int g    = lane & 3;
    int qrow = lane >> 4;
    int dl   = (lane >> 2) & 3;
    #pragma unroll
    for (int j = 0; j < 4; ++j) {
        int ncol_base = w * 64 + j * 16;
        int d = (ncol_base >> 2) + dl;
        float b0 = bias[0 * 128 + d];
        float b1 = bias[1 * 128 + d];
        float b2 = bias[2 * 128 + d];
        float b3 = bias[3 * 128 + d];
        #pragma unroll
        for (int i = 0; i < 2; ++i) {
            f4_t A = acc[i][j];
            float s0 = pickv(A, g);
            float s1 = pickv(A, g ^ 1);
            float s2 = pickv(A, g ^ 2);
            float s3 = pickv(A, g ^ 3);
            float u0 = s0;
            float u1 = __shfl_xor(s1, 1);
            float u2 = __shfl_xor(s2, 2);
            float u3 = __shfl_xor(s3, 3);
            float p0 = pick4(u0, u1, u2, u3, g) + b0;
            float p1 = pick4(u0, u1, u2, u3, g ^ 1) + b1;
            float p2 = pick4(u0, u1, u2, u3, g ^ 2) + b2;
            float p3 = pick4(u0, u1, u2, u3, g ^ 3) + b3;
            float ig = sigm_(p0);
            float og = sigm_(p1);
            float fg = sigm_(p2);
            float cg = tanh_(p3);
            int row = row0 + i * 16 + qrow * 4 + g;
            size_t off = (size_t)row * H_ + d;
            float c_old = c_src[off];
            float c_new = fg * c_old + ig * cg;
            c_dst[off] = c_new;
            h_dst[off] = og * tanh_(c_new);
        }
    }
}

extern "C" void kernel_launch(void* const* d_in, const int* in_sizes, int n_in,
                              void* d_out, int out_size, void* d_ws, size_t ws_size,
                              hipStream_t stream) {
    const float* node_hidden = (const float*)d_in[0];
    const float* cell        = (const float*)d_in[1];
    const float* w_in        = (const float*)d_in[2];
    const float* w_out       = (const float*)d_in[3];
    const float* u_in        = (const float*)d_in[4];
    const float* u_out       = (const float*)d_in[5];
    const float* bias        = (const float*)d_in[6];
    const float* in_mask     = (const float*)d_in[7];
    const float* out_mask    = (const float*)d_in[8];
    const int*   in_idx      = (const int*)d_in[9];
    const int*   out_idx     = (const int*)d_in[10];
    float* out = (float*)d_out;

    char* p = (char*)d_ws;
    unsigned short* wp_hi = (unsigned short*)p; p += (size_t)NTILES * NCHUNK * 512 * 2; // 384 KB
    unsigned short* wp_lo = (unsigned short*)p; p += (size_t)NTILES * NCHUNK * 512 * 2;
    float* h_buf = (float*)p;                   p += (size_t)M_ * H_ * 4;              // 8 MB
    float* c_buf = (float*)p;                   p += (size_t)M_ * H_ * 4;              // 8 MB

    prep_kernel<<<NTILES * NCHUNK, 512, 0, stream>>>(w_in, w_out, u_in, u_out, wp_hi, wp_lo);

    // layer 0: h = node_hidden, c = cell -> h_buf, c_buf
    fused_layer<<<M_ / 32, 512, 0, stream>>>(
        node_hidden, in_idx, in_mask, out_idx, out_mask,
        wp_hi, wp_lo, bias, cell, c_buf, h_buf);

    // layer 1: h = h_buf, c = c_buf -> out, c_buf
    fused_layer<<<M_ / 32, 512, 0, stream>>>(
        h_buf, in_idx, in_mask, out_idx, out_mask,
        wp_hi, wp_lo, bias, c_buf, c_buf, out);
}

// Round 4
// 210.021 us; speedup vs baseline: 1.0371x; 1.0371x over previous
//
#include <hip/hip_runtime.h>
#include <math.h>

#define B_ 8
#define N_ 2000
#define H_ 128
#define K_ 32
#define M_ (B_*N_)     // 16000
#define KTOT 384       // [in_agg(128) | out_agg(128) | h(128)]
#define NC 512         // cols j = d*4 + g
#define NTILES 32      // NC/16
#define NCHUNK 12      // KTOT/32
#define ACHUNK 8       // chunks stored in A-frag buffer (in/out agg only)

typedef __attribute__((ext_vector_type(8))) short s8_t;
typedef __attribute__((ext_vector_type(4))) float f4_t;

__device__ __forceinline__ unsigned short f2bf(float x) {
    union { float f; unsigned u; } v; v.f = x;
    unsigned r = v.u + 0x7fff + ((v.u >> 16) & 1);   // RN-even
    return (unsigned short)(r >> 16);
}
__device__ __forceinline__ float bf2f(unsigned short b) {
    union { unsigned u; float f; } v; v.u = (unsigned)b << 16; return v.f;
}
__device__ __forceinline__ float sigm_(float x) { return 1.f / (1.f + __expf(-x)); }
__device__ __forceinline__ float tanh_(float x) { return 2.f / (1.f + __expf(-2.f * x)) - 1.f; }

__device__ __forceinline__ float pickv(f4_t A, int m) {
    float ab = (m & 1) ? A.y : A.x;
    float cd = (m & 1) ? A.w : A.z;
    return (m & 2) ? cd : ab;
}
__device__ __forceinline__ float pick4(float u0, float u1, float u2, float u3, int m) {
    float ab = (m & 1) ? u1 : u0;
    float cd = (m & 1) ? u3 : u2;
    return (m & 2) ? cd : ab;
}

// W in per-lane MFMA B-fragment order: (ntile, chunk, lane, e) =
// W[col = ntile*16 + (lane&15)][k = chunk*32 + (lane>>4)*8 + e], col j = d*4+g.
__global__ __launch_bounds__(512)
void prep_kernel(const float* __restrict__ w_in,
                 const float* __restrict__ w_out,
                 const float* __restrict__ u_in,
                 const float* __restrict__ u_out,
                 unsigned short* __restrict__ wp_hi,
                 unsigned short* __restrict__ wp_lo) {
    int blk = blockIdx.x;            // ntile*NCHUNK + chunk
    int ntile = blk / NCHUNK, chunk = blk % NCHUNK;
    int t = threadIdx.x;
    int lane = t >> 3, e = t & 7;
    int col = ntile * 16 + (lane & 15);
    int k = chunk * 32 + (lane >> 4) * 8 + e;
    int d = col >> 2, g = col & 3;
    float v;
    if (k < 128) {
        v = w_in[(g * 128 + k) * 128 + d];
    } else if (k < 256) {
        v = w_out[(g * 128 + (k - 128)) * 128 + d];
    } else {
        int kk = k - 256;
        v = u_in[(g * 128 + kk) * 128 + d] + u_out[(g * 128 + kk) * 128 + d];
    }
    unsigned short hs = f2bf(v);
    wp_hi[(size_t)blk * 512 + t] = hs;
    wp_lo[(size_t)blk * 512 + t] = f2bf(v - bf2f(hs));
}

// Gather + masked aggregate; output split-bf16 directly in MFMA A-fragment
// layout: A[(mtile*8 + c)*64 + lane]*8 shorts, lane = (m&15) + 16*kg,
// element e -> k = c*32 + kg*8 + e. Chunks 0..3 = in_agg, 4..7 = out_agg.
__global__ __launch_bounds__(256)
void agg_kernel(const float* __restrict__ h,
                const int* __restrict__ in_idx,
                const float* __restrict__ in_mask,
                const int* __restrict__ out_idx,
                const float* __restrict__ out_mask,
                unsigned short* __restrict__ A_hi,
                unsigned short* __restrict__ A_lo) {
    int tid = threadIdx.x;
    int r = tid >> 5;            // 0..7 row within block
    int p = tid & 31;            // dim group: dims p*4 .. p*4+3
    int row = blockIdx.x * 8 + r;
    int b = row / N_;
    const float* hb = h + (size_t)b * N_ * H_;

    __shared__ int   s_idx[8][64];
    __shared__ float s_msk[8][64];
    for (int e = tid; e < 512; e += 256) {
        int r2 = e >> 6, q = e & 63;
        int ridx = blockIdx.x * 8 + r2;
        if (q < 32) {
            s_idx[r2][q] = in_idx[ridx * K_ + q];
            s_msk[r2][q] = in_mask[ridx * K_ + q];
        } else {
            s_idx[r2][q] = out_idx[ridx * K_ + (q - 32)];
            s_msk[r2][q] = out_mask[ridx * K_ + (q - 32)];
        }
    }
    __syncthreads();

    int d0 = p * 4;
    float ai[4] = {0.f, 0.f, 0.f, 0.f};
    float ao[4] = {0.f, 0.f, 0.f, 0.f};
    #pragma unroll 4
    for (int k = 0; k < K_; ++k) {
        int   i1 = s_idx[r][k];
        float m1 = s_msk[r][k];
        int   i2 = s_idx[r][32 + k];
        float m2 = s_msk[r][32 + k];
        float4 v1 = *(const float4*)(hb + (size_t)i1 * H_ + d0);
        float4 v2 = *(const float4*)(hb + (size_t)i2 * H_ + d0);
        ai[0] += m1 * v1.x; ai[1] += m1 * v1.y; ai[2] += m1 * v1.z; ai[3] += m1 * v1.w;
        ao[0] += m2 * v2.x; ao[1] += m2 * v2.y; ao[2] += m2 * v2.z; ao[3] += m2 * v2.w;
    }

    // pack to fragment layout
    int mtile = row >> 4;
    int kg = (p >> 1) & 3;
    int e0 = (p & 1) * 4;
    int lane = (row & 15) + 16 * kg;
    size_t bi = ((size_t)(mtile * ACHUNK + (p >> 3)) * 64 + lane) * 8 + e0;
    size_t bo = ((size_t)(mtile * ACHUNK + 4 + (p >> 3)) * 64 + lane) * 8 + e0;

    ushort4 hi_i, lo_i, hi_o, lo_o;
    {
        unsigned short h0 = f2bf(ai[0]), h1 = f2bf(ai[1]), h2 = f2bf(ai[2]), h3 = f2bf(ai[3]);
        hi_i = make_ushort4(h0, h1, h2, h3);
        lo_i = make_ushort4(f2bf(ai[0] - bf2f(h0)), f2bf(ai[1] - bf2f(h1)),
                            f2bf(ai[2] - bf2f(h2)), f2bf(ai[3] - bf2f(h3)));
        unsigned short g0 = f2bf(ao[0]), g1 = f2bf(ao[1]), g2 = f2bf(ao[2]), g3 = f2bf(ao[3]);
        hi_o = make_ushort4(g0, g1, g2, g3);
        lo_o = make_ushort4(f2bf(ao[0] - bf2f(g0)), f2bf(ao[1] - bf2f(g1)),
                            f2bf(ao[2] - bf2f(g2)), f2bf(ao[3] - bf2f(g3)));
    }
    *(ushort4*)(A_hi + bi) = hi_i;
    *(ushort4*)(A_lo + bi) = lo_i;
    *(ushort4*)(A_hi + bo) = hi_o;
    *(ushort4*)(A_lo + bo) = lo_o;
}

// Barrier-free, LDS-free MFMA GEMM + fused LSTM gates.
// Block tile 64 rows x 128 cols; 4 waves, wave tile 32x64.
// A chunks 0..7 from fragment buffer; chunks 8..11 converted from fp32 h rows.
__global__ __launch_bounds__(256, 4)
void gemm_gates(const unsigned short* __restrict__ A_hi,
                const unsigned short* __restrict__ A_lo,
                const float* __restrict__ h_src,
                const unsigned short* __restrict__ wp_hi,
                const unsigned short* __restrict__ wp_lo,
                const float* __restrict__ bias,
                const float* __restrict__ c_src,
                float* __restrict__ c_dst,
                float* __restrict__ h_dst,
                int write_c) {
    int tid  = threadIdx.x;
    int mt   = blockIdx.x;       // 0..249
    int jt   = blockIdx.y;       // 0..3
    int lane = tid & 63;
    int w    = tid >> 6;         // 0..3
    int row0 = mt * 64;
    int m_off = (w & 1) * 32;
    int n_off = (w >> 1) * 64;
    int ml = lane & 15;
    int kg = lane >> 4;

    int mtile0 = mt * 4 + (w & 1) * 2;
    int ntile0 = jt * 8 + (w >> 1) * 4;

    f4_t zero = {0.f, 0.f, 0.f, 0.f};
    f4_t acc[2][4];
    #pragma unroll
    for (int i = 0; i < 2; ++i)
        #pragma unroll
        for (int j = 0; j < 4; ++j) acc[i][j] = zero;

    // ---- chunks 0..7: aggregate part, fragments straight from L2 ----
    #pragma unroll 1
    for (int c = 0; c < ACHUNK; ++c) {
        s8_t a_hi[2], a_lo[2], b_hi[4], b_lo[4];
        #pragma unroll
        for (int i = 0; i < 2; ++i) {
            size_t off = ((size_t)((mtile0 + i) * ACHUNK + c) * 64 + lane) * 8;
            a_hi[i] = *(const s8_t*)(A_hi + off);
            a_lo[i] = *(const s8_t*)(A_lo + off);
        }
        #pragma unroll
        for (int j = 0; j < 4; ++j) {
            size_t boff = ((size_t)((ntile0 + j) * NCHUNK + c) * 64 + lane) * 8;
            b_hi[j] = *(const s8_t*)(wp_hi + boff);
            b_lo[j] = *(const s8_t*)(wp_lo + boff);
        }
        #pragma unroll
        for (int i = 0; i < 2; ++i)
            #pragma unroll
            for (int j = 0; j < 4; ++j) {
                acc[i][j] = __builtin_amdgcn_mfma_f32_16x16x32_bf16(a_hi[i], b_hi[j], acc[i][j], 0, 0, 0);
                acc[i][j] = __builtin_amdgcn_mfma_f32_16x16x32_bf16(a_hi[i], b_lo[j], acc[i][j], 0, 0, 0);
                acc[i][j] = __builtin_amdgcn_mfma_f32_16x16x32_bf16(a_lo[i], b_hi[j], acc[i][j], 0, 0, 0);
            }
    }

    // ---- chunks 8..11: u-term, convert fp32 h rows to split-bf16 frags ----
    #pragma unroll 1
    for (int c = ACHUNK; c < NCHUNK; ++c) {
        s8_t a_hi[2], a_lo[2], b_hi[4], b_lo[4];
        #pragma unroll
        for (int i = 0; i < 2; ++i) {
            const float* ph = h_src + (size_t)(row0 + m_off + i * 16 + ml) * H_
                              + (c - ACHUNK) * 32 + kg * 8;
            float4 f0 = *(const float4*)ph;
            float4 f1 = *(const float4*)(ph + 4);
            float fv[8] = {f0.x, f0.y, f0.z, f0.w, f1.x, f1.y, f1.z, f1.w};
            s8_t hv, lv;
            #pragma unroll
            for (int e = 0; e < 8; ++e) {
                unsigned short hs = f2bf(fv[e]);
                hv[e] = (short)hs;
                lv[e] = (short)f2bf(fv[e] - bf2f(hs));
            }
            a_hi[i] = hv;
            a_lo[i] = lv;
        }
        #pragma unroll
        for (int j = 0; j < 4; ++j) {
            size_t boff = ((size_t)((ntile0 + j) * NCHUNK + c) * 64 + lane) * 8;
            b_hi[j] = *(const s8_t*)(wp_hi + boff);
            b_lo[j] = *(const s8_t*)(wp_lo + boff);
        }
        #pragma unroll
        for (int i = 0; i < 2; ++i)
            #pragma unroll
            for (int j = 0; j < 4; ++j) {
                acc[i][j] = __builtin_amdgcn_mfma_f32_16x16x32_bf16(a_hi[i], b_hi[j], acc[i][j], 0, 0, 0);
                acc[i][j] = __builtin_amdgcn_mfma_f32_16x16x32_bf16(a_hi[i], b_lo[j], acc[i][j], 0, 0, 0);
                acc[i][j] = __builtin_amdgcn_mfma_f32_16x16x32_bf16(a_lo[i], b_hi[j], acc[i][j], 0, 0, 0);
            }
    }

    // ---- epilogue: gate exchange + cell/h update (verified in R2/R3) ----
    int g    = lane & 3;
    int qrow = lane >> 4;
    int dl   = (lane >> 2) & 3;
    #pragma unroll
    for (int j = 0; j < 4; ++j) {
        int ncol_base = jt * 128 + n_off + j * 16;
        int d = (ncol_base >> 2) + dl;
        float b0 = bias[0 * 128 + d];
        float b1 = bias[1 * 128 + d];
        float b2 = bias[2 * 128 + d];
        float b3 = bias[3 * 128 + d];
        #pragma unroll
        for (int i = 0; i < 2; ++i) {
            f4_t A = acc[i][j];
            float s0 = pickv(A, g);
            float s1 = pickv(A, g ^ 1);
            float s2 = pickv(A, g ^ 2);
            float s3 = pickv(A, g ^ 3);
            float u0 = s0;
            float u1 = __shfl_xor(s1, 1);
            float u2 = __shfl_xor(s2, 2);
            float u3 = __shfl_xor(s3, 3);
            float p0 = pick4(u0, u1, u2, u3, g) + b0;
            float p1 = pick4(u0, u1, u2, u3, g ^ 1) + b1;
            float p2 = pick4(u0, u1, u2, u3, g ^ 2) + b2;
            float p3 = pick4(u0, u1, u2, u3, g ^ 3) + b3;
            float ig = sigm_(p0);
            float og = sigm_(p1);
            float fg = sigm_(p2);
            float cg = tanh_(p3);
            int row = row0 + m_off + i * 16 + qrow * 4 + g;
            size_t off = (size_t)row * H_ + d;
            float c_old = c_src[off];
            float c_new = fg * c_old + ig * cg;
            if (write_c) c_dst[off] = c_new;
            h_dst[off] = og * tanh_(c_new);
        }
    }
}

extern "C" void kernel_launch(void* const* d_in, const int* in_sizes, int n_in,
                              void* d_out, int out_size, void* d_ws, size_t ws_size,
                              hipStream_t stream) {
    const float* node_hidden = (const float*)d_in[0];
    const float* cell        = (const float*)d_in[1];
    const float* w_in        = (const float*)d_in[2];
    const float* w_out       = (const float*)d_in[3];
    const float* u_in        = (const float*)d_in[4];
    const float* u_out       = (const float*)d_in[5];
    const float* bias        = (const float*)d_in[6];
    const float* in_mask     = (const float*)d_in[7];
    const float* out_mask    = (const float*)d_in[8];
    const int*   in_idx      = (const int*)d_in[9];
    const int*   out_idx     = (const int*)d_in[10];
    float* out = (float*)d_out;

    char* p = (char*)d_ws;
    unsigned short* wp_hi = (unsigned short*)p; p += (size_t)NTILES * NCHUNK * 512 * 2;      // 384 KB
    unsigned short* wp_lo = (unsigned short*)p; p += (size_t)NTILES * NCHUNK * 512 * 2;
    unsigned short* A_hi  = (unsigned short*)p; p += (size_t)(M_/16) * ACHUNK * 512 * 2;     // 8 MB
    unsigned short* A_lo  = (unsigned short*)p; p += (size_t)(M_/16) * ACHUNK * 512 * 2;
    float* h_buf = (float*)p;                   p += (size_t)M_ * H_ * 4;                    // 8 MB
    // total ~25 MB; layer-0 c lives in d_out (overwritten by layer-1 h)

    prep_kernel<<<NTILES * NCHUNK, 512, 0, stream>>>(w_in, w_out, u_in, u_out, wp_hi, wp_lo);

    // layer 0: h=node_hidden, c=cell -> c into d_out, h into h_buf
    agg_kernel<<<M_ / 8, 256, 0, stream>>>(node_hidden, in_idx, in_mask,
                                           out_idx, out_mask, A_hi, A_lo);
    gemm_gates<<<dim3(M_ / 64, 4), 256, 0, stream>>>(
        A_hi, A_lo, node_hidden, wp_hi, wp_lo, bias, cell, out, h_buf, 1);

    // layer 1: h=h_buf, c=d_out -> final h into d_out (c discarded)
    agg_kernel<<<M_ / 8, 256, 0, stream>>>(h_buf, in_idx, in_mask,
                                           out_idx, out_mask, A_hi, A_lo);
    gemm_gates<<<dim3(M_ / 64, 4), 256, 0, stream>>>(
        A_hi, A_lo, h_buf, wp_hi, wp_lo, bias, out, out, out, 0);
}

// Round 5
// 207.164 us; speedup vs baseline: 1.0514x; 1.0138x over previous
//
#include <hip/hip_runtime.h>
#include <math.h>

#define B_ 8
#define N_ 2000
#define H_ 128
#define K_ 32
#define M_ (B_*N_)     // 16000
#define KTOT 384       // [in_agg(128) | out_agg(128) | h(128)]
#define NC 512         // cols j = d*4 + g
#define NTILES 32      // NC/16
#define NCHUNK 12      // KTOT/32

typedef __attribute__((ext_vector_type(8))) short s8_t;
typedef __attribute__((ext_vector_type(4))) float f4_t;

__device__ __forceinline__ unsigned short f2bf(float x) {
    union { float f; unsigned u; } v; v.f = x;
    unsigned r = v.u + 0x7fff + ((v.u >> 16) & 1);   // RN-even
    return (unsigned short)(r >> 16);
}
__device__ __forceinline__ float bf2f(unsigned short b) {
    union { unsigned u; float f; } v; v.u = (unsigned)b << 16; return v.f;
}
__device__ __forceinline__ float sigm_(float x) { return 1.f / (1.f + __expf(-x)); }
__device__ __forceinline__ float tanh_(float x) { return 2.f / (1.f + __expf(-2.f * x)) - 1.f; }

__device__ __forceinline__ float pickv(f4_t A, int m) {
    float ab = (m & 1) ? A.y : A.x;
    float cd = (m & 1) ? A.w : A.z;
    return (m & 2) ? cd : ab;
}
__device__ __forceinline__ float pick4(float u0, float u1, float u2, float u3, int m) {
    float ab = (m & 1) ? u1 : u0;
    float cd = (m & 1) ? u3 : u2;
    return (m & 2) ? cd : ab;
}

__device__ __forceinline__ void split4(const float* f, ushort4& hi, ushort4& lo) {
    unsigned short h0 = f2bf(f[0]), h1 = f2bf(f[1]), h2 = f2bf(f[2]), h3 = f2bf(f[3]);
    hi = make_ushort4(h0, h1, h2, h3);
    lo = make_ushort4(f2bf(f[0] - bf2f(h0)), f2bf(f[1] - bf2f(h1)),
                      f2bf(f[2] - bf2f(h2)), f2bf(f[3] - bf2f(h3)));
}

// W in per-lane MFMA B-fragment order: (ntile, chunk, lane, e) =
// W[col = ntile*16 + (lane&15)][k = chunk*32 + (lane>>4)*8 + e], col j = d*4+g.
__global__ __launch_bounds__(512)
void prep_kernel(const float* __restrict__ w_in,
                 const float* __restrict__ w_out,
                 const float* __restrict__ u_in,
                 const float* __restrict__ u_out,
                 unsigned short* __restrict__ wp_hi,
                 unsigned short* __restrict__ wp_lo) {
    int blk = blockIdx.x;            // ntile*NCHUNK + chunk
    int ntile = blk / NCHUNK, chunk = blk % NCHUNK;
    int t = threadIdx.x;
    int lane = t >> 3, e = t & 7;
    int col = ntile * 16 + (lane & 15);
    int k = chunk * 32 + (lane >> 4) * 8 + e;
    int d = col >> 2, g = col & 3;
    float v;
    if (k < 128) {
        v = w_in[(g * 128 + k) * 128 + d];
    } else if (k < 256) {
        v = w_out[(g * 128 + (k - 128)) * 128 + d];
    } else {
        int kk = k - 256;
        v = u_in[(g * 128 + kk) * 128 + d] + u_out[(g * 128 + kk) * 128 + d];
    }
    unsigned short hs = f2bf(v);
    wp_hi[(size_t)blk * 512 + t] = hs;
    wp_lo[(size_t)blk * 512 + t] = f2bf(v - bf2f(hs));
}

// Gather + masked aggregate + u-term pack; output split-bf16 in MFMA A-fragment
// layout: A[(mtile*12 + c)*64 + lane]*8 shorts, lane = (m&15) + 16*kg,
// k = c*32 + kg*8 + e. Chunks 0..3 in_agg, 4..7 out_agg, 8..11 own h row.
// Block-index swizzle pins each batch b to one XCD (dispatch is i%8 round-robin)
// so the 1 MB h-slice gathers stay local-L2-resident.
__global__ __launch_bounds__(256)
void agg_kernel(const float* __restrict__ h,
                const int* __restrict__ in_idx,
                const float* __restrict__ in_mask,
                const int* __restrict__ out_idx,
                const float* __restrict__ out_mask,
                unsigned short* __restrict__ A_hi,
                unsigned short* __restrict__ A_lo) {
    int bid = (blockIdx.x & 7) * 250 + (blockIdx.x >> 3);   // XCD-affinity swizzle
    int tid = threadIdx.x;
    int r = tid >> 5;            // 0..7 row within block
    int p = tid & 31;            // dim group: dims p*4 .. p*4+3
    int row = bid * 8 + r;
    int b = row / N_;
    const float* hb = h + (size_t)b * N_ * H_;

    __shared__ int   s_idx[8][64];
    __shared__ float s_msk[8][64];
    for (int e = tid; e < 512; e += 256) {
        int r2 = e >> 6, q = e & 63;
        int ridx = bid * 8 + r2;
        if (q < 32) {
            s_idx[r2][q] = in_idx[ridx * K_ + q];
            s_msk[r2][q] = in_mask[ridx * K_ + q];
        } else {
            s_idx[r2][q] = out_idx[ridx * K_ + (q - 32)];
            s_msk[r2][q] = out_mask[ridx * K_ + (q - 32)];
        }
    }
    __syncthreads();

    int d0 = p * 4;
    float ai[4] = {0.f, 0.f, 0.f, 0.f};
    float ao[4] = {0.f, 0.f, 0.f, 0.f};
    #pragma unroll 4
    for (int k = 0; k < K_; ++k) {
        int   i1 = s_idx[r][k];
        float m1 = s_msk[r][k];
        int   i2 = s_idx[r][32 + k];
        float m2 = s_msk[r][32 + k];
        float4 v1 = *(const float4*)(hb + (size_t)i1 * H_ + d0);
        float4 v2 = *(const float4*)(hb + (size_t)i2 * H_ + d0);
        ai[0] += m1 * v1.x; ai[1] += m1 * v1.y; ai[2] += m1 * v1.z; ai[3] += m1 * v1.w;
        ao[0] += m2 * v2.x; ao[1] += m2 * v2.y; ao[2] += m2 * v2.z; ao[3] += m2 * v2.w;
    }
    // own h row (u-term input)
    float4 hv4 = *(const float4*)(h + (size_t)row * H_ + d0);
    float hh[4] = {hv4.x, hv4.y, hv4.z, hv4.w};

    // fragment positions: same k<->(chunk,kg,e) arithmetic for all three parts
    int mtile = row >> 4;
    int kg = (p >> 1) & 3;
    int e0 = (p & 1) * 4;
    int lane = (row & 15) + 16 * kg;
    size_t bi = ((size_t)(mtile * NCHUNK +     (p >> 3)) * 64 + lane) * 8 + e0;
    size_t bo = ((size_t)(mtile * NCHUNK + 4 + (p >> 3)) * 64 + lane) * 8 + e0;
    size_t bh = ((size_t)(mtile * NCHUNK + 8 + (p >> 3)) * 64 + lane) * 8 + e0;

    ushort4 hi, lo;
    split4(ai, hi, lo); *(ushort4*)(A_hi + bi) = hi; *(ushort4*)(A_lo + bi) = lo;
    split4(ao, hi, lo); *(ushort4*)(A_hi + bo) = hi; *(ushort4*)(A_lo + bo) = lo;
    split4(hh, hi, lo); *(ushort4*)(A_hi + bh) = hi; *(ushort4*)(A_lo + bh) = lo;
}

// Barrier-free, LDS-free MFMA GEMM + fused LSTM gates.
// Block tile 64 rows x 128 cols; 4 waves, wave tile 32x64.
// All operands stream from L2 in per-lane fragment order; 2-stage SW pipeline.
__global__ __launch_bounds__(256)
void gemm_gates(const unsigned short* __restrict__ A_hi,
                const unsigned short* __restrict__ A_lo,
                const unsigned short* __restrict__ wp_hi,
                const unsigned short* __restrict__ wp_lo,
                const float* __restrict__ bias,
                const float* __restrict__ c_src,
                float* __restrict__ c_dst,
                float* __restrict__ h_dst,
                int write_c) {
    int tid  = threadIdx.x;
    int mt   = blockIdx.x;       // 0..249
    int jt   = blockIdx.y;       // 0..3
    int lane = tid & 63;
    int w    = tid >> 6;         // 0..3
    int row0 = mt * 64;
    int m_off = (w & 1) * 32;
    int n_off = (w >> 1) * 64;

    int mtile0 = mt * 4 + (w & 1) * 2;
    int ntile0 = jt * 8 + (w >> 1) * 4;

    const unsigned short* pa0 = A_hi + ((size_t)mtile0 * NCHUNK * 64 + lane) * 8;
    const unsigned short* pa1 = A_lo + ((size_t)mtile0 * NCHUNK * 64 + lane) * 8;
    const unsigned short* pb0 = wp_hi + ((size_t)ntile0 * NCHUNK * 64 + lane) * 8;
    const unsigned short* pb1 = wp_lo + ((size_t)ntile0 * NCHUNK * 64 + lane) * 8;
    const size_t mstride = (size_t)NCHUNK * 512;   // shorts per tile row of chunks
    const size_t cstride = 512;

    f4_t zero = {0.f, 0.f, 0.f, 0.f};
    f4_t acc[2][4];
    #pragma unroll
    for (int i = 0; i < 2; ++i)
        #pragma unroll
        for (int j = 0; j < 4; ++j) acc[i][j] = zero;

    s8_t ahA[2], alA[2], bhA[4], blA[4];
    s8_t ahB[2], alB[2], bhB[4], blB[4];

#define LOADF(ah, al, bh, bl, c)                                              \
    {                                                                         \
        _Pragma("unroll")                                                     \
        for (int i = 0; i < 2; ++i) {                                         \
            ah[i] = *(const s8_t*)(pa0 + i * mstride + (c) * cstride);        \
            al[i] = *(const s8_t*)(pa1 + i * mstride + (c) * cstride);        \
        }                                                                     \
        _Pragma("unroll")                                                     \
        for (int j = 0; j < 4; ++j) {                                         \
            bh[j] = *(const s8_t*)(pb0 + j * mstride + (c) * cstride);        \
            bl[j] = *(const s8_t*)(pb1 + j * mstride + (c) * cstride);        \
        }                                                                     \
    }

#define MFMAF(ah, al, bh, bl)                                                 \
    {                                                                         \
        _Pragma("unroll")                                                     \
        for (int i = 0; i < 2; ++i)                                           \
            _Pragma("unroll")                                                 \
            for (int j = 0; j < 4; ++j) {                                     \
                acc[i][j] = __builtin_amdgcn_mfma_f32_16x16x32_bf16(ah[i], bh[j], acc[i][j], 0, 0, 0); \
                acc[i][j] = __builtin_amdgcn_mfma_f32_16x16x32_bf16(ah[i], bl[j], acc[i][j], 0, 0, 0); \
                acc[i][j] = __builtin_amdgcn_mfma_f32_16x16x32_bf16(al[i], bh[j], acc[i][j], 0, 0, 0); \
            }                                                                 \
    }

    LOADF(ahA, alA, bhA, blA, 0)
    #pragma unroll
    for (int c = 0; c < NCHUNK; c += 2) {
        LOADF(ahB, alB, bhB, blB, c + 1)
        MFMAF(ahA, alA, bhA, blA)
        if (c + 2 < NCHUNK) LOADF(ahA, alA, bhA, blA, c + 2)
        MFMAF(ahB, alB, bhB, blB)
    }
#undef LOADF
#undef MFMAF

    // ---- epilogue: gate exchange + cell/h update (verified R2-R4) ----
    int g    = lane & 3;
    int qrow = lane >> 4;
    int dl   = (lane >> 2) & 3;
    #pragma unroll
    for (int j = 0; j < 4; ++j) {
        int ncol_base = jt * 128 + n_off + j * 16;
        int d = (ncol_base >> 2) + dl;
        float b0 = bias[0 * 128 + d];
        float b1 = bias[1 * 128 + d];
        float b2 = bias[2 * 128 + d];
        float b3 = bias[3 * 128 + d];
        #pragma unroll
        for (int i = 0; i < 2; ++i) {
            f4_t A = acc[i][j];
            float s0 = pickv(A, g);
            float s1 = pickv(A, g ^ 1);
            float s2 = pickv(A, g ^ 2);
            float s3 = pickv(A, g ^ 3);
            float u0 = s0;
            float u1 = __shfl_xor(s1, 1);
            float u2 = __shfl_xor(s2, 2);
            float u3 = __shfl_xor(s3, 3);
            float p0 = pick4(u0, u1, u2, u3, g) + b0;
            float p1 = pick4(u0, u1, u2, u3, g ^ 1) + b1;
            float p2 = pick4(u0, u1, u2, u3, g ^ 2) + b2;
            float p3 = pick4(u0, u1, u2, u3, g ^ 3) + b3;
            float ig = sigm_(p0);
            float og = sigm_(p1);
            float fg = sigm_(p2);
            float cg = tanh_(p3);
            int row = row0 + m_off + i * 16 + qrow * 4 + g;
            size_t off = (size_t)row * H_ + d;
            float c_old = c_src[off];
            float c_new = fg * c_old + ig * cg;
            if (write_c) c_dst[off] = c_new;
            h_dst[off] = og * tanh_(c_new);
        }
    }
}

extern "C" void kernel_launch(void* const* d_in, const int* in_sizes, int n_in,
                              void* d_out, int out_size, void* d_ws, size_t ws_size,
                              hipStream_t stream) {
    const float* node_hidden = (const float*)d_in[0];
    const float* cell        = (const float*)d_in[1];
    const float* w_in        = (const float*)d_in[2];
    const float* w_out       = (const float*)d_in[3];
    const float* u_in        = (const float*)d_in[4];
    const float* u_out       = (const float*)d_in[5];
    const float* bias        = (const float*)d_in[6];
    const float* in_mask     = (const float*)d_in[7];
    const float* out_mask    = (const float*)d_in[8];
    const int*   in_idx      = (const int*)d_in[9];
    const int*   out_idx     = (const int*)d_in[10];
    float* out = (float*)d_out;

    char* p = (char*)d_ws;
    unsigned short* wp_hi = (unsigned short*)p; p += (size_t)NTILES * NCHUNK * 512 * 2;      // 384 KB
    unsigned short* wp_lo = (unsigned short*)p; p += (size_t)NTILES * NCHUNK * 512 * 2;
    unsigned short* A_hi  = (unsigned short*)p; p += (size_t)(M_/16) * NCHUNK * 512 * 2;     // 12 MB
    unsigned short* A_lo  = (unsigned short*)p; p += (size_t)(M_/16) * NCHUNK * 512 * 2;
    float* h_buf = (float*)p;                   p += (size_t)M_ * H_ * 4;                    // 8 MB
    // total ~33 MB; layer-0 c lives in d_out (overwritten by layer-1 h)

    prep_kernel<<<NTILES * NCHUNK, 512, 0, stream>>>(w_in, w_out, u_in, u_out, wp_hi, wp_lo);

    // layer 0: h=node_hidden, c=cell -> c into d_out, h into h_buf
    agg_kernel<<<M_ / 8, 256, 0, stream>>>(node_hidden, in_idx, in_mask,
                                           out_idx, out_mask, A_hi, A_lo);
    gemm_gates<<<dim3(M_ / 64, 4), 256, 0, stream>>>(
        A_hi, A_lo, wp_hi, wp_lo, bias, cell, out, h_buf, 1);

    // layer 1: h=h_buf, c=d_out -> final h into d_out (c discarded)
    agg_kernel<<<M_ / 8, 256, 0, stream>>>(h_buf, in_idx, in_mask,
                                           out_idx, out_mask, A_hi, A_lo);
    gemm_gates<<<dim3(M_ / 64, 4), 256, 0, stream>>>(
        A_hi, A_lo, wp_hi, wp_lo, bias, out, out, out, 0);
}

// Round 6
// 191.742 us; speedup vs baseline: 1.1359x; 1.0804x over previous
//
#include <hip/hip_runtime.h>
#include <math.h>

#define B_ 8
#define N_ 2000
#define H_ 128
#define K_ 32
#define M_ (B_*N_)     // 16000
#define KTOT 384       // [in_agg(128) | out_agg(128) | h(128)]
#define NC 512         // cols j = d*4 + g
#define NTILES 32      // NC/16
#define NCHUNK 12      // KTOT/32

typedef __attribute__((ext_vector_type(8))) short s8_t;
typedef __attribute__((ext_vector_type(4))) float f4_t;

__device__ __forceinline__ unsigned short f2bf(float x) {
    union { float f; unsigned u; } v; v.f = x;
    unsigned r = v.u + 0x7fff + ((v.u >> 16) & 1);   // RN-even
    return (unsigned short)(r >> 16);
}
__device__ __forceinline__ float bf2f(unsigned short b) {
    union { unsigned u; float f; } v; v.u = (unsigned)b << 16; return v.f;
}
__device__ __forceinline__ float sigm_(float x) { return 1.f / (1.f + __expf(-x)); }
__device__ __forceinline__ float tanh_(float x) { return 2.f / (1.f + __expf(-2.f * x)) - 1.f; }

__device__ __forceinline__ float pickv(f4_t A, int m) {
    float ab = (m & 1) ? A.y : A.x;
    float cd = (m & 1) ? A.w : A.z;
    return (m & 2) ? cd : ab;
}
__device__ __forceinline__ float pick4(float u0, float u1, float u2, float u3, int m) {
    float ab = (m & 1) ? u1 : u0;
    float cd = (m & 1) ? u3 : u2;
    return (m & 2) ? cd : ab;
}

__device__ __forceinline__ void split4(const float* f, ushort4& hi, ushort4& lo) {
    unsigned short h0 = f2bf(f[0]), h1 = f2bf(f[1]), h2 = f2bf(f[2]), h3 = f2bf(f[3]);
    hi = make_ushort4(h0, h1, h2, h3);
    lo = make_ushort4(f2bf(f[0] - bf2f(h0)), f2bf(f[1] - bf2f(h1)),
                      f2bf(f[2] - bf2f(h2)), f2bf(f[3] - bf2f(h3)));
}

// async global->LDS, 16 B per lane; LDS dest = wave-uniform base + lane*16
__device__ __forceinline__ void gload_lds(const unsigned short* g, short* l) {
    __builtin_amdgcn_global_load_lds(
        (const __attribute__((address_space(1))) unsigned*)g,
        (__attribute__((address_space(3))) unsigned*)l, 16, 0, 0);
}

// W in per-lane MFMA B-fragment order: (ntile, chunk, lane, e) =
// W[col = ntile*16 + (lane&15)][k = chunk*32 + (lane>>4)*8 + e], col j = d*4+g.
__global__ __launch_bounds__(512)
void prep_kernel(const float* __restrict__ w_in,
                 const float* __restrict__ w_out,
                 const float* __restrict__ u_in,
                 const float* __restrict__ u_out,
                 unsigned short* __restrict__ wp_hi,
                 unsigned short* __restrict__ wp_lo) {
    int blk = blockIdx.x;            // ntile*NCHUNK + chunk
    int ntile = blk / NCHUNK, chunk = blk % NCHUNK;
    int t = threadIdx.x;
    int lane = t >> 3, e = t & 7;
    int col = ntile * 16 + (lane & 15);
    int k = chunk * 32 + (lane >> 4) * 8 + e;
    int d = col >> 2, g = col & 3;
    float v;
    if (k < 128) {
        v = w_in[(g * 128 + k) * 128 + d];
    } else if (k < 256) {
        v = w_out[(g * 128 + (k - 128)) * 128 + d];
    } else {
        int kk = k - 256;
        v = u_in[(g * 128 + kk) * 128 + d] + u_out[(g * 128 + kk) * 128 + d];
    }
    unsigned short hs = f2bf(v);
    wp_hi[(size_t)blk * 512 + t] = hs;
    wp_lo[(size_t)blk * 512 + t] = f2bf(v - bf2f(hs));
}

// Gather + masked aggregate + u-term pack; output split-bf16 in MFMA A-fragment
// layout: A[(mtile*12 + c)*64 + lane]*8 shorts, lane = (m&15) + 16*kg,
// k = c*32 + kg*8 + e. Chunks 0..3 in_agg, 4..7 out_agg, 8..11 own h row.
__global__ __launch_bounds__(256)
void agg_kernel(const float* __restrict__ h,
                const int* __restrict__ in_idx,
                const float* __restrict__ in_mask,
                const int* __restrict__ out_idx,
                const float* __restrict__ out_mask,
                unsigned short* __restrict__ A_hi,
                unsigned short* __restrict__ A_lo) {
    int bid = (blockIdx.x & 7) * 250 + (blockIdx.x >> 3);   // XCD-affinity swizzle
    int tid = threadIdx.x;
    int r = tid >> 5;            // 0..7 row within block
    int p = tid & 31;            // dim group: dims p*4 .. p*4+3
    int row = bid * 8 + r;
    int b = row / N_;
    const float* hb = h + (size_t)b * N_ * H_;

    __shared__ int   s_idx[8][64];
    __shared__ float s_msk[8][64];
    for (int e = tid; e < 512; e += 256) {
        int r2 = e >> 6, q = e & 63;
        int ridx = bid * 8 + r2;
        if (q < 32) {
            s_idx[r2][q] = in_idx[ridx * K_ + q];
            s_msk[r2][q] = in_mask[ridx * K_ + q];
        } else {
            s_idx[r2][q] = out_idx[ridx * K_ + (q - 32)];
            s_msk[r2][q] = out_mask[ridx * K_ + (q - 32)];
        }
    }
    __syncthreads();

    int d0 = p * 4;
    float ai[4] = {0.f, 0.f, 0.f, 0.f};
    float ao[4] = {0.f, 0.f, 0.f, 0.f};
    #pragma unroll 8
    for (int k = 0; k < K_; ++k) {
        int   i1 = s_idx[r][k];
        float m1 = s_msk[r][k];
        int   i2 = s_idx[r][32 + k];
        float m2 = s_msk[r][32 + k];
        float4 v1 = *(const float4*)(hb + (size_t)i1 * H_ + d0);
        float4 v2 = *(const float4*)(hb + (size_t)i2 * H_ + d0);
        ai[0] += m1 * v1.x; ai[1] += m1 * v1.y; ai[2] += m1 * v1.z; ai[3] += m1 * v1.w;
        ao[0] += m2 * v2.x; ao[1] += m2 * v2.y; ao[2] += m2 * v2.z; ao[3] += m2 * v2.w;
    }
    // own h row (u-term input)
    float4 hv4 = *(const float4*)(h + (size_t)row * H_ + d0);
    float hh[4] = {hv4.x, hv4.y, hv4.z, hv4.w};

    int mtile = row >> 4;
    int kg = (p >> 1) & 3;
    int e0 = (p & 1) * 4;
    int lane = (row & 15) + 16 * kg;
    size_t bi = ((size_t)(mtile * NCHUNK +     (p >> 3)) * 64 + lane) * 8 + e0;
    size_t bo = ((size_t)(mtile * NCHUNK + 4 + (p >> 3)) * 64 + lane) * 8 + e0;
    size_t bh = ((size_t)(mtile * NCHUNK + 8 + (p >> 3)) * 64 + lane) * 8 + e0;

    ushort4 hi, lo;
    split4(ai, hi, lo); *(ushort4*)(A_hi + bi) = hi; *(ushort4*)(A_lo + bi) = lo;
    split4(ao, hi, lo); *(ushort4*)(A_hi + bo) = hi; *(ushort4*)(A_lo + bo) = lo;
    split4(hh, hi, lo); *(ushort4*)(A_hi + bh) = hi; *(ushort4*)(A_lo + bh) = lo;
}

// m97-style MFMA GEMM + fused LSTM gates. Block tile 128x128 (8 mtiles x
// 8 ntiles), 4 waves, wave tile 64x64. Per chunk: 32 KB staged to LDS via
// global_load_lds (32 slots x 1 KB, lane-linear), 2-barrier K-loop.
__global__ __launch_bounds__(256)
void gemm_gates(const unsigned short* __restrict__ A_hi,
                const unsigned short* __restrict__ A_lo,
                const unsigned short* __restrict__ wp_hi,
                const unsigned short* __restrict__ wp_lo,
                const float* __restrict__ bias,
                const float* __restrict__ c_src,
                float* __restrict__ c_dst,
                float* __restrict__ h_dst,
                int write_c) {
    __shared__ short sL[32 * 512];   // 32 KB: slots 0..7 A_hi, 8..15 A_lo,
                                     // 16..23 W_hi, 24..31 W_lo
    int tid  = threadIdx.x;
    int mt   = blockIdx.x;       // 0..124 -> mtiles 8mt..8mt+7
    int jt   = blockIdx.y;       // 0..3   -> ntiles 8jt..8jt+7
    int lane = tid & 63;
    int w    = tid >> 6;         // 0..3
    int wm   = w & 1;            // mtile half
    int wn   = w >> 1;           // ntile half
    int mtile0 = mt * 8;
    int ntile0 = jt * 8;

    // staging: wave w owns slots {w, w+4, ..., w+28}
    const unsigned short* gp[8];
    short* lp[8];
    #pragma unroll
    for (int i = 0; i < 8; ++i) {
        int s = i * 4 + w;
        const unsigned short* src;
        if (s < 8)       src = A_hi  + ((size_t)((mtile0 + s)      * NCHUNK) * 64 + lane) * 8;
        else if (s < 16) src = A_lo  + ((size_t)((mtile0 + s - 8)  * NCHUNK) * 64 + lane) * 8;
        else if (s < 24) src = wp_hi + ((size_t)((ntile0 + s - 16) * NCHUNK) * 64 + lane) * 8;
        else             src = wp_lo + ((size_t)((ntile0 + s - 24) * NCHUNK) * 64 + lane) * 8;
        gp[i] = src;
        lp[i] = &sL[s * 512];    // wave-uniform base; HW adds lane*16 B
    }

    f4_t zero = {0.f, 0.f, 0.f, 0.f};
    f4_t acc[4][4];
    #pragma unroll
    for (int i = 0; i < 4; ++i)
        #pragma unroll
        for (int j = 0; j < 4; ++j) acc[i][j] = zero;

    #pragma unroll 1
    for (int c = 0; c < NCHUNK; ++c) {
        if (c > 0) __syncthreads();          // previous chunk's LDS reads done
        #pragma unroll
        for (int i = 0; i < 8; ++i) {
            gload_lds(gp[i], lp[i]);
            gp[i] += 512;                    // next chunk (512 shorts = 1 KB)
        }
        __syncthreads();                     // drains vmcnt -> LDS ready

        s8_t a_hi[4], a_lo[4], b_hi[4], b_lo[4];
        #pragma unroll
        for (int i = 0; i < 4; ++i) {
            a_hi[i] = *(const s8_t*)&sL[(wm * 4 + i) * 512 + lane * 8];
            a_lo[i] = *(const s8_t*)&sL[(8 + wm * 4 + i) * 512 + lane * 8];
        }
        #pragma unroll
        for (int j = 0; j < 4; ++j) {
            b_hi[j] = *(const s8_t*)&sL[(16 + wn * 4 + j) * 512 + lane * 8];
            b_lo[j] = *(const s8_t*)&sL[(24 + wn * 4 + j) * 512 + lane * 8];
        }
        #pragma unroll
        for (int i = 0; i < 4; ++i)
            #pragma unroll
            for (int j = 0; j < 4; ++j) {
                acc[i][j] = __builtin_amdgcn_mfma_f32_16x16x32_bf16(a_hi[i], b_hi[j], acc[i][j], 0, 0, 0);
                acc[i][j] = __builtin_amdgcn_mfma_f32_16x16x32_bf16(a_hi[i], b_lo[j], acc[i][j], 0, 0, 0);
                acc[i][j] = __builtin_amdgcn_mfma_f32_16x16x32_bf16(a_lo[i], b_hi[j], acc[i][j], 0, 0, 0);
            }
    }

    // ---- epilogue: gate exchange + cell/h update (verified R2-R5) ----
    int g    = lane & 3;
    int qrow = lane >> 4;
    int dl   = (lane >> 2) & 3;
    #pragma unroll
    for (int j = 0; j < 4; ++j) {
        int ncol_base = jt * 128 + wn * 64 + j * 16;
        int d = (ncol_base >> 2) + dl;
        float b0 = bias[0 * 128 + d];
        float b1 = bias[1 * 128 + d];
        float b2 = bias[2 * 128 + d];
        float b3 = bias[3 * 128 + d];
        #pragma unroll
        for (int i = 0; i < 4; ++i) {
            f4_t A = acc[i][j];
            float s0 = pickv(A, g);
            float s1 = pickv(A, g ^ 1);
            float s2 = pickv(A, g ^ 2);
            float s3 = pickv(A, g ^ 3);
            float u0 = s0;
            float u1 = __shfl_xor(s1, 1);
            float u2 = __shfl_xor(s2, 2);
            float u3 = __shfl_xor(s3, 3);
            float p0 = pick4(u0, u1, u2, u3, g) + b0;
            float p1 = pick4(u0, u1, u2, u3, g ^ 1) + b1;
            float p2 = pick4(u0, u1, u2, u3, g ^ 2) + b2;
            float p3 = pick4(u0, u1, u2, u3, g ^ 3) + b3;
            float ig = sigm_(p0);
            float og = sigm_(p1);
            float fg = sigm_(p2);
            float cg = tanh_(p3);
            int row = mt * 128 + wm * 64 + i * 16 + qrow * 4 + g;
            size_t off = (size_t)row * H_ + d;
            float c_old = c_src[off];
            float c_new = fg * c_old + ig * cg;
            if (write_c) c_dst[off] = c_new;
            h_dst[off] = og * tanh_(c_new);
        }
    }
}

extern "C" void kernel_launch(void* const* d_in, const int* in_sizes, int n_in,
                              void* d_out, int out_size, void* d_ws, size_t ws_size,
                              hipStream_t stream) {
    const float* node_hidden = (const float*)d_in[0];
    const float* cell        = (const float*)d_in[1];
    const float* w_in        = (const float*)d_in[2];
    const float* w_out       = (const float*)d_in[3];
    const float* u_in        = (const float*)d_in[4];
    const float* u_out       = (const float*)d_in[5];
    const float* bias        = (const float*)d_in[6];
    const float* in_mask     = (const float*)d_in[7];
    const float* out_mask    = (const float*)d_in[8];
    const int*   in_idx      = (const int*)d_in[9];
    const int*   out_idx     = (const int*)d_in[10];
    float* out = (float*)d_out;

    char* p = (char*)d_ws;
    unsigned short* wp_hi = (unsigned short*)p; p += (size_t)NTILES * NCHUNK * 512 * 2;      // 384 KB
    unsigned short* wp_lo = (unsigned short*)p; p += (size_t)NTILES * NCHUNK * 512 * 2;
    unsigned short* A_hi  = (unsigned short*)p; p += (size_t)(M_/16) * NCHUNK * 512 * 2;     // 12 MB
    unsigned short* A_lo  = (unsigned short*)p; p += (size_t)(M_/16) * NCHUNK * 512 * 2;
    float* h_buf = (float*)p;                   p += (size_t)M_ * H_ * 4;                    // 8 MB
    // total ~33 MB; layer-0 c lives in d_out (overwritten by layer-1 h)

    prep_kernel<<<NTILES * NCHUNK, 512, 0, stream>>>(w_in, w_out, u_in, u_out, wp_hi, wp_lo);

    // layer 0: h=node_hidden, c=cell -> c into d_out, h into h_buf
    agg_kernel<<<M_ / 8, 256, 0, stream>>>(node_hidden, in_idx, in_mask,
                                           out_idx, out_mask, A_hi, A_lo);
    gemm_gates<<<dim3(M_ / 128, 4), 256, 0, stream>>>(
        A_hi, A_lo, wp_hi, wp_lo, bias, cell, out, h_buf, 1);

    // layer 1: h=h_buf, c=d_out -> final h into d_out (c discarded)
    agg_kernel<<<M_ / 8, 256, 0, stream>>>(h_buf, in_idx, in_mask,
                                           out_idx, out_mask, A_hi, A_lo);
    gemm_gates<<<dim3(M_ / 128, 4), 256, 0, stream>>>(
        A_hi, A_lo, wp_hi, wp_lo, bias, out, out, out, 0);
}